// Round 10
// baseline (22126.393 us; speedup 1.0000x reference)
//
#include <hip/hip_runtime.h>
#include <cstdint>
#include <cstddef>

#define BB 64
#define TT 512
#define II 256
#define HH 256
#define GG 768   // 3*H

typedef _Float16 f16x2 __attribute__((ext_vector_type(2)));
typedef _Float16 f16x8 __attribute__((ext_vector_type(8)));
typedef float    f32x4 __attribute__((ext_vector_type(4)));

__device__ __forceinline__ float sigf(float x)       { return 1.f / (1.f + __expf(-x)); }
__device__ __forceinline__ float tanh_fast(float x)  { return 1.f - 2.f / (__expf(2.f * x) + 1.f); }

__device__ __forceinline__ uint32_t packf16(float a, float b) {
    f16x2 v; v.x = (_Float16)a; v.y = (_Float16)b;
    return __builtin_bit_cast(uint32_t, v);
}
__device__ __forceinline__ float cvt16(uint32_t u) {
    return (float)__builtin_bit_cast(_Float16, (unsigned short)(u & 0xffffu));
}

// 2 MACs via v_fma_mix_f32 (fpext-f16 fma pattern; full-rate VALU)
__device__ __forceinline__ float mac2(uint32_t w, uint32_t h, float acc) {
    f16x2 a = __builtin_bit_cast(f16x2, w), b = __builtin_bit_cast(f16x2, h);
    acc = fmaf((float)a.x, (float)b.x, acc);
    acc = fmaf((float)a.y, (float)b.y, acc);
    return acc;
}

// quad_perm add: acc += value from quad lane permutation (explicit indices)
template <int CTRL>
__device__ __forceinline__ float qadd(float v) {
    int y = __builtin_amdgcn_update_dpp(0, __builtin_bit_cast(int, v),
                                        CTRL, 0xf, 0xf, true);
    return v + __builtin_bit_cast(float, y);
}

// ---------------------------------------------------------------------------
// Kernel A: pack Wh for the 512-thread k-split scan (R7 layout, verified).
// Scan thread t (0..511): chunk c = t&3 (k in [c*64,(c+1)*64)), rows
// r(t,j) = j*128 + (t>>2), j = 0..5.  wf[j*32+m] = f16x2(Wh[r][c*64+2m], +1).
// Global layout: wpk[d][jm*512 + t], jm = j*32+m in [0,192).
// ---------------------------------------------------------------------------
__global__ void pack_wh(const float* __restrict__ Whf,
                        const float* __restrict__ Whb,
                        uint32_t* __restrict__ wpk)
{
    int idx = blockIdx.x * 256 + threadIdx.x;   // 0 .. 196607
    int d = idx >= 98304;
    int u = idx - d * 98304;                    // 0 .. 98303
    int t  = u & 511;
    int jm = u >> 9;                            // 0 .. 191
    int j = jm >> 5, m = jm & 31;
    int r = j * 128 + (t >> 2);
    int c = t & 3;
    const float* __restrict__ W = d ? Whb : Whf;
    const float* base = &W[(size_t)r * II + c * 64 + 2 * m];
    wpk[(size_t)d * 98304 + (size_t)jm * 512 + t] = packf16(base[0], base[1]);
}

// ---------------------------------------------------------------------------
// Kernel B: MFMA f16 GEMM for gi (byte-identical to R8/R9, verified).
// gi2[m][col-pair] = f16x2( x.Wi + bi + (G<2 ? bh : 0) ), row = 384 u32.
// ---------------------------------------------------------------------------
__global__ __launch_bounds__(256) void gi_gemm_mfma2(
    const float* __restrict__ x,
    const float* __restrict__ Wif, const float* __restrict__ bif,
    const float* __restrict__ Wib, const float* __restrict__ bib,
    const float* __restrict__ bhf, const float* __restrict__ bhb,
    uint32_t* __restrict__ gi2)
{
    __shared__ __align__(16) _Float16 Asm[8][64][8];   // 8 KB
    __shared__ __align__(16) _Float16 Bsm[8][64][8];   // 8 KB

    const int ntile = blockIdx.x % 12;
    const int mtile = blockIdx.x / 12;
    const int m0 = mtile * 64;
    const int n0 = ntile * 64;
    const int d  = m0 >> 15;
    const int xrow0 = m0 & 32767;
    const float* __restrict__ W      = d ? Wib : Wif;
    const float* __restrict__ bias_i = d ? bib : bif;
    const float* __restrict__ bias_h = d ? bhb : bhf;

    const int tid  = threadIdx.x;
    const int w    = tid >> 6;
    const int lane = tid & 63;
    const int lr   = lane & 15;
    const int lk8  = (lane >> 4);

    f32x4 acc[4] = {};

    const int srow = tid >> 2;
    const int scol = (tid & 3) * 16;

    for (int k0 = 0; k0 < II; k0 += 64) {
        const float* ap = &x[(size_t)(xrow0 + srow) * II + k0 + scol];
        const float* bp = &W[(size_t)(n0 + srow)   * II + k0 + scol];
#pragma unroll
        for (int half = 0; half < 2; ++half) {
            float4 a0 = *(const float4*)(ap + 8 * half);
            float4 a1 = *(const float4*)(ap + 8 * half + 4);
            float4 b0 = *(const float4*)(bp + 8 * half);
            float4 b1 = *(const float4*)(bp + 8 * half + 4);
            f16x8 av, bv;
            av[0] = (_Float16)a0.x; av[1] = (_Float16)a0.y;
            av[2] = (_Float16)a0.z; av[3] = (_Float16)a0.w;
            av[4] = (_Float16)a1.x; av[5] = (_Float16)a1.y;
            av[6] = (_Float16)a1.z; av[7] = (_Float16)a1.w;
            bv[0] = (_Float16)b0.x; bv[1] = (_Float16)b0.y;
            bv[2] = (_Float16)b0.z; bv[3] = (_Float16)b0.w;
            bv[4] = (_Float16)b1.x; bv[5] = (_Float16)b1.y;
            bv[6] = (_Float16)b1.z; bv[7] = (_Float16)b1.w;
            *(f16x8*)&Asm[scol / 8 + half][srow][0] = av;
            *(f16x8*)&Bsm[scol / 8 + half][srow][0] = bv;
        }
        __syncthreads();

#pragma unroll
        for (int kk = 0; kk < 2; ++kk) {
            const int kb = kk * 4 + lk8;
            f16x8 af = *(const f16x8*)&Asm[kb][16 * w + lr][0];
#pragma unroll
            for (int j = 0; j < 4; ++j) {
                f16x8 bf = *(const f16x8*)&Bsm[kb][16 * j + lr][0];
                acc[j] = __builtin_amdgcn_mfma_f32_16x16x32_f16(af, bf, acc[j], 0, 0, 0);
            }
        }
        __syncthreads();
    }

    const int rbase = m0 + 16 * w + (lane >> 4) * 4;
#pragma unroll
    for (int j = 0; j < 4; ++j) {
        const int col = n0 + 16 * j + lr;
        float bsum = bias_i[col] + ((n0 < 512) ? bias_h[col] : 0.f);
#pragma unroll
        for (int r = 0; r < 4; ++r) {
            float v  = acc[j][r] + bsum;
            float vn = __shfl_down(v, 1);
            if (!(lane & 1)) {
                gi2[(size_t)(rbase + r) * 384 + (col >> 1)] = packf16(v, vn);
            }
        }
    }
}

// ---------------------------------------------------------------------------
// Kernel C: R7 scan structure with fma_mix MACs.  512 threads (2 waves/SIMD).
// Thread t: a=t>>2, q=t&3; chunk c=q, rows {j*128+a} j=0..5 (192 u32 wf).
// Per step: 8 uint4 broadcast h reads, 384 fma_mix into 12 split accs,
// quad-DPP butterfly, in-register gates (gi2 f16, bias-folded), 1 barrier.
// ---------------------------------------------------------------------------
__global__ __launch_bounds__(512, 2) void gru_scan_mix(
    const uint32_t* __restrict__ gi2,   // [2*64][512][384] u32 (f16x2 col-pairs)
    const uint32_t* __restrict__ wpk,
    const float* __restrict__ h0f, const float* __restrict__ h0b,
    const float* __restrict__ bhf, const float* __restrict__ bhb,
    float* __restrict__ out)
{
    __shared__ __align__(16) uint32_t hpk[2][4 * 36];  // 4 chunks, 32 u32 + 4 pad

    const int bx = blockIdx.x;
    const int d  = bx >> 6;
    const int b  = bx & 63;
    const int t  = threadIdx.x;       // 0..511
    const int a  = t >> 2;            // 0..127
    const int q  = t & 3;             // quad slot == k-chunk c
    const int o  = (q < 2) ? a : (128 + a);   // owned output index

    const float* __restrict__ bh = d ? bhb : bhf;
    const float* __restrict__ h0 = d ? h0b : h0f;

    // ---- weights into registers (coalesced; one-time) ----
    const uint32_t* __restrict__ wp = wpk + (size_t)d * 98304;
    uint32_t wf[192];
#pragma unroll
    for (int jm = 0; jm < 192; ++jm) wf[jm] = wp[(size_t)jm * 512 + t];

    // ---- h0: register h_prev + packed f16x2 into hpk[0] ----
    float hp = h0[(size_t)b * HH + o];
    {
        float hnb = __shfl_down(hp, 4);       // output o+1's value (even a)
        if (!(a & 1) && !(q & 1)) {           // q==0 (m=a/2) or q==2 (m=64+a/2)
            int m = (q == 0) ? (a >> 1) : (64 + (a >> 1));
            hpk[0][(m >> 5) * 36 + (m & 31)] = packf16(hp, hnb);
        }
    }

    // n-gate recurrent bias (r/z bh folded into gi2 by the GEMM)
    const float bbn = bh[512 + o];

    const int dir = d ? -1 : 1;
    int ta = d ? (TT - 1) : 0;
    const uint32_t* __restrict__ g2 =
        gi2 + ((size_t)(d * 64 + b) * TT + ta) * 384;
    const int gco = o >> 1;
    const int shf = (a & 1) * 16;

    uint32_t gr = g2[gco], gz = g2[128 + gco], gn = g2[256 + gco];

    __syncthreads();

    for (int s = 0; s < TT; ++s) {
        const int cur = s & 1;

        const uint32_t grc = gr, gzc = gz, gnc = gn;
        if (s + 1 < TT) {
            g2 += (ptrdiff_t)dir * 384;
            gr = g2[gco]; gz = g2[128 + gco]; gn = g2[256 + gco];
        }

        // ---- dot phase: 8 uint4 broadcast reads, 384 fma_mix, 12 accs ----
        const uint32_t* __restrict__ hb = &hpk[cur][q * 36];
        float accA[6] = {}, accB[6] = {};
#pragma unroll
        for (int q8 = 0; q8 < 8; ++q8) {
            uint4 h4 = *(const uint4*)&hb[q8 * 4];
#pragma unroll
            for (int j = 0; j < 6; ++j) {
                accA[j] = mac2(wf[j * 32 + q8 * 4 + 0], h4.x, accA[j]);
                accB[j] = mac2(wf[j * 32 + q8 * 4 + 1], h4.y, accB[j]);
                accA[j] = mac2(wf[j * 32 + q8 * 4 + 2], h4.z, accA[j]);
                accB[j] = mac2(wf[j * 32 + q8 * 4 + 3], h4.w, accB[j]);
            }
        }

        float acc[6];
#pragma unroll
        for (int j = 0; j < 6; ++j) acc[j] = accA[j] + accB[j];

        // ---- quad butterfly: every lane gets full row sums (no LDS) ----
#pragma unroll
        for (int j = 0; j < 6; ++j) {
            acc[j] = qadd<0xB1>(acc[j]);   // quad_perm [1,0,3,2]  (xor 1)
            acc[j] = qadd<0x4E>(acc[j]);   // quad_perm [2,3,0,1]  (xor 2)
        }

        // output a (q<2): r=acc[0], z=acc[2], n=acc[4]
        // output 128+a (q>=2): r=acc[1], z=acc[3], n=acc[5]
        float hr = (q < 2) ? acc[0] : acc[1];
        float hz = (q < 2) ? acc[2] : acc[3];
        float hn = ((q < 2) ? acc[4] : acc[5]) + bbn;

        float ir  = cvt16(grc >> shf);
        float iz  = cvt16(gzc >> shf);
        float inn = cvt16(gnc >> shf);

        float rg = sigf(ir + hr);
        float zg = sigf(iz + hz);
        float ng = tanh_fast(fmaf(rg, hn, inn));
        float hnew = tanh_fast(fmaf(zg, hp - ng, ng));
        hp = hnew;
        if (!(q & 1))
            out[((size_t)b * TT + ta) * (2 * HH) + d * HH + o] = hnew;

        float hnb = __shfl_down(hnew, 4);     // output o+1's value (even a)
        if (!(a & 1) && !(q & 1)) {
            int m = (q == 0) ? (a >> 1) : (64 + (a >> 1));
            hpk[cur ^ 1][(m >> 5) * 36 + (m & 31)] = packf16(hnew, hnb);
        }
        ta += dir;
        __syncthreads();
    }
}

// ---------------------------------------------------------------------------
// Fallback scan (ws too small): unchanged known-good path.
// ---------------------------------------------------------------------------
__global__ __launch_bounds__(768) void gru_scan_fallback(
    const float* __restrict__ x,
    const float* __restrict__ h0f, const float* __restrict__ h0b,
    const float* __restrict__ Wif, const float* __restrict__ bif_,
    const float* __restrict__ Whf, const float* __restrict__ bhf,
    const float* __restrict__ Wib, const float* __restrict__ bib_,
    const float* __restrict__ Whb, const float* __restrict__ bhb,
    float* __restrict__ out)
{
    __shared__ __align__(16) float hbuf[2][HH];
    __shared__ float gh_s[GG];
    __shared__ float gi_s[GG];
    __shared__ __align__(16) float xrow[II];

    const int bx  = blockIdx.x;
    const int d   = bx >> 6;
    const int b   = bx & 63;
    const int tid = threadIdx.x;

    const float* __restrict__ Wh = d ? Whb : Whf;
    const float* __restrict__ bh = d ? bhb : bhf;
    const float* __restrict__ Wi = d ? Wib : Wif;
    const float* __restrict__ bi = d ? bib_ : bif_;
    const float* __restrict__ h0 = d ? h0b : h0f;

    if (tid < HH) hbuf[0][tid] = h0[(size_t)b * HH + tid];

    const float bh_row = bh[tid];
    const float bi_row = bi[tid];
    const float4* __restrict__ whr = (const float4*)(Wh + (size_t)tid * II);
    const float4* __restrict__ wir = (const float4*)(Wi + (size_t)tid * II);

    __syncthreads();

    for (int s = 0; s < TT; ++s) {
        const int ta  = d ? (TT - 1 - s) : s;
        const int cur = s & 1;

        if (tid < II) xrow[tid] = x[((size_t)b * TT + ta) * II + tid];
        __syncthreads();

        const float4* hv4 = (const float4*)hbuf[cur];
        float a0 = 0.f, a1 = 0.f, a2 = 0.f, a3 = 0.f;
#pragma unroll 4
        for (int k = 0; k < II / 4; k += 4) {
            float4 w0 = whr[k], w1 = whr[k + 1], w2 = whr[k + 2], w3 = whr[k + 3];
            float4 q0 = hv4[k], q1 = hv4[k + 1], q2 = hv4[k + 2], q3 = hv4[k + 3];
            a0 += w0.x * q0.x + w0.y * q0.y + w0.z * q0.z + w0.w * q0.w;
            a1 += w1.x * q1.x + w1.y * q1.y + w1.z * q1.z + w1.w * q1.w;
            a2 += w2.x * q2.x + w2.y * q2.y + w2.z * q2.z + w2.w * q2.w;
            a3 += w3.x * q3.x + w3.y * q3.y + w3.z * q3.z + w3.w * q3.w;
        }
        gh_s[tid] = (a0 + a1) + (a2 + a3) + bh_row;

        const float4* xv4 = (const float4*)xrow;
        float c0 = 0.f, c1 = 0.f, c2 = 0.f, c3 = 0.f;
#pragma unroll 4
        for (int k = 0; k < II / 4; k += 4) {
            float4 w0 = wir[k], w1 = wir[k + 1], w2 = wir[k + 2], w3 = wir[k + 3];
            float4 q0 = xv4[k], q1 = xv4[k + 1], q2 = xv4[k + 2], q3 = xv4[k + 3];
            c0 += w0.x * q0.x + w0.y * q0.y + w0.z * q0.z + w0.w * q0.w;
            c1 += w1.x * q1.x + w1.y * q1.y + w1.z * q1.z + w1.w * q1.w;
            c2 += w2.x * q2.x + w2.y * q2.y + w2.z * q2.z + w2.w * q2.w;
            c3 += w3.x * q3.x + w3.y * q3.y + w3.z * q3.z + w3.w * q3.w;
        }
        gi_s[tid] = (c0 + c1) + (c2 + c3) + bi_row;
        __syncthreads();

        if (tid < HH) {
            float ir = gi_s[tid], iz = gi_s[HH + tid], inn = gi_s[2 * HH + tid];
            float hr = gh_s[tid], hz = gh_s[HH + tid], hn = gh_s[2 * HH + tid];
            float r  = sigf(ir + hr);
            float z  = sigf(iz + hz);
            float n  = tanh_fast(inn + r * hn);
            float hp = hbuf[cur][tid];
            float hnew = tanh_fast((1.f - z) * n + z * hp);
            hbuf[cur ^ 1][tid] = hnew;
            out[((size_t)b * TT + ta) * (2 * HH) + d * HH + tid] = hnew;
        }
        __syncthreads();
    }
}

// ---------------------------------------------------------------------------
extern "C" void kernel_launch(void* const* d_in, const int* in_sizes, int n_in,
                              void* d_out, int out_size, void* d_ws, size_t ws_size,
                              hipStream_t stream)
{
    const float* x   = (const float*)d_in[0];
    const float* h0f = (const float*)d_in[1];
    const float* h0b = (const float*)d_in[2];
    const float* Wif = (const float*)d_in[3];
    const float* Whf = (const float*)d_in[4];
    const float* bif = (const float*)d_in[5];
    const float* bhf = (const float*)d_in[6];
    const float* Wib = (const float*)d_in[7];
    const float* Whb = (const float*)d_in[8];
    const float* bib = (const float*)d_in[9];
    const float* bhb = (const float*)d_in[10];
    float* out = (float*)d_out;

    const size_t gi2_bytes = (size_t)2 * BB * TT * 384 * sizeof(uint32_t); // 100,663,296
    const size_t wpk_bytes = (size_t)2 * 98304 * sizeof(uint32_t);        //     786,432

    if (ws_size >= gi2_bytes + wpk_bytes) {
        uint32_t* gi2 = (uint32_t*)d_ws;
        uint32_t* wpk = (uint32_t*)((char*)d_ws + gi2_bytes);

        pack_wh<<<768, 256, 0, stream>>>(Whf, Whb, wpk);

        gi_gemm_mfma2<<<12288, 256, 0, stream>>>(x, Wif, bif, Wib, bib,
                                                 bhf, bhb, gi2);

        gru_scan_mix<<<128, 512, 0, stream>>>(gi2, wpk, h0f, h0b, bhf, bhb, out);
    } else {
        gru_scan_fallback<<<128, 768, 0, stream>>>(
            x, h0f, h0b, Wif, bif, Whf, bhf, Wib, bib, Whb, bhb, out);
    }
}

// Round 11
// 769.442 us; speedup vs baseline: 28.7564x; 28.7564x over previous
//
#include <hip/hip_runtime.h>
#include <cstdint>
#include <cstddef>

#define BB 64
#define TT 512
#define II 256
#define HH 256
#define GG 768   // 3*H

typedef _Float16 f16x2 __attribute__((ext_vector_type(2)));
typedef _Float16 f16x8 __attribute__((ext_vector_type(8)));
typedef float    f32x4 __attribute__((ext_vector_type(4)));

__device__ __forceinline__ float sigf(float x)       { return 1.f / (1.f + __expf(-x)); }
__device__ __forceinline__ float tanh_fast(float x)  { return 1.f - 2.f / (__expf(2.f * x) + 1.f); }

__device__ __forceinline__ uint32_t packf16(float a, float b) {
    f16x2 v; v.x = (_Float16)a; v.y = (_Float16)b;
    return __builtin_bit_cast(uint32_t, v);
}
__device__ __forceinline__ float cvt16(uint32_t u) {
    return (float)__builtin_bit_cast(_Float16, (unsigned short)(u & 0xffffu));
}

// packed f16 FMA: 2 MACs in ONE v_pk_fma_f16 (operands stay packed u32)
__device__ __forceinline__ f16x2 pkfma(uint32_t w, uint32_t h, f16x2 acc) {
    return __builtin_bit_cast(f16x2, w) * __builtin_bit_cast(f16x2, h) + acc;
}

// quad_perm add: acc += value from quad lane permutation (explicit indices)
template <int CTRL>
__device__ __forceinline__ float qadd(float v) {
    int y = __builtin_amdgcn_update_dpp(0, __builtin_bit_cast(int, v),
                                        CTRL, 0xf, 0xf, true);
    return v + __builtin_bit_cast(float, y);
}

// ---------------------------------------------------------------------------
// Kernel A: pack Wh for the 512-thread k-split scan (R7 layout, verified).
// Scan thread t (0..511): chunk c = t&3 (k in [c*64,(c+1)*64)), rows
// r(t,j) = j*128 + (t>>2), j = 0..5.  wf[j*32+m] = f16x2(Wh[r][c*64+2m], +1).
// Global layout: wpk[d][jm*512 + t], jm = j*32+m in [0,192).
// ---------------------------------------------------------------------------
__global__ void pack_wh(const float* __restrict__ Whf,
                        const float* __restrict__ Whb,
                        uint32_t* __restrict__ wpk)
{
    int idx = blockIdx.x * 256 + threadIdx.x;   // 0 .. 196607
    int d = idx >= 98304;
    int u = idx - d * 98304;                    // 0 .. 98303
    int t  = u & 511;
    int jm = u >> 9;                            // 0 .. 191
    int j = jm >> 5, m = jm & 31;
    int r = j * 128 + (t >> 2);
    int c = t & 3;
    const float* __restrict__ W = d ? Whb : Whf;
    const float* base = &W[(size_t)r * II + c * 64 + 2 * m];
    wpk[(size_t)d * 98304 + (size_t)jm * 512 + t] = packf16(base[0], base[1]);
}

// ---------------------------------------------------------------------------
// Kernel B: MFMA f16 GEMM for gi (byte-identical to R8/R9/R10, verified).
// gi2[m][col-pair] = f16x2( x.Wi + bi + (G<2 ? bh : 0) ), row = 384 u32.
// ---------------------------------------------------------------------------
__global__ __launch_bounds__(256) void gi_gemm_mfma2(
    const float* __restrict__ x,
    const float* __restrict__ Wif, const float* __restrict__ bif,
    const float* __restrict__ Wib, const float* __restrict__ bib,
    const float* __restrict__ bhf, const float* __restrict__ bhb,
    uint32_t* __restrict__ gi2)
{
    __shared__ __align__(16) _Float16 Asm[8][64][8];   // 8 KB
    __shared__ __align__(16) _Float16 Bsm[8][64][8];   // 8 KB

    const int ntile = blockIdx.x % 12;
    const int mtile = blockIdx.x / 12;
    const int m0 = mtile * 64;
    const int n0 = ntile * 64;
    const int d  = m0 >> 15;
    const int xrow0 = m0 & 32767;
    const float* __restrict__ W      = d ? Wib : Wif;
    const float* __restrict__ bias_i = d ? bib : bif;
    const float* __restrict__ bias_h = d ? bhb : bhf;

    const int tid  = threadIdx.x;
    const int w    = tid >> 6;
    const int lane = tid & 63;
    const int lr   = lane & 15;
    const int lk8  = (lane >> 4);

    f32x4 acc[4] = {};

    const int srow = tid >> 2;
    const int scol = (tid & 3) * 16;

    for (int k0 = 0; k0 < II; k0 += 64) {
        const float* ap = &x[(size_t)(xrow0 + srow) * II + k0 + scol];
        const float* bp = &W[(size_t)(n0 + srow)   * II + k0 + scol];
#pragma unroll
        for (int half = 0; half < 2; ++half) {
            float4 a0 = *(const float4*)(ap + 8 * half);
            float4 a1 = *(const float4*)(ap + 8 * half + 4);
            float4 b0 = *(const float4*)(bp + 8 * half);
            float4 b1 = *(const float4*)(bp + 8 * half + 4);
            f16x8 av, bv;
            av[0] = (_Float16)a0.x; av[1] = (_Float16)a0.y;
            av[2] = (_Float16)a0.z; av[3] = (_Float16)a0.w;
            av[4] = (_Float16)a1.x; av[5] = (_Float16)a1.y;
            av[6] = (_Float16)a1.z; av[7] = (_Float16)a1.w;
            bv[0] = (_Float16)b0.x; bv[1] = (_Float16)b0.y;
            bv[2] = (_Float16)b0.z; bv[3] = (_Float16)b0.w;
            bv[4] = (_Float16)b1.x; bv[5] = (_Float16)b1.y;
            bv[6] = (_Float16)b1.z; bv[7] = (_Float16)b1.w;
            *(f16x8*)&Asm[scol / 8 + half][srow][0] = av;
            *(f16x8*)&Bsm[scol / 8 + half][srow][0] = bv;
        }
        __syncthreads();

#pragma unroll
        for (int kk = 0; kk < 2; ++kk) {
            const int kb = kk * 4 + lk8;
            f16x8 af = *(const f16x8*)&Asm[kb][16 * w + lr][0];
#pragma unroll
            for (int j = 0; j < 4; ++j) {
                f16x8 bf = *(const f16x8*)&Bsm[kb][16 * j + lr][0];
                acc[j] = __builtin_amdgcn_mfma_f32_16x16x32_f16(af, bf, acc[j], 0, 0, 0);
            }
        }
        __syncthreads();
    }

    const int rbase = m0 + 16 * w + (lane >> 4) * 4;
#pragma unroll
    for (int j = 0; j < 4; ++j) {
        const int col = n0 + 16 * j + lr;
        float bsum = bias_i[col] + ((n0 < 512) ? bias_h[col] : 0.f);
#pragma unroll
        for (int r = 0; r < 4; ++r) {
            float v  = acc[j][r] + bsum;
            float vn = __shfl_down(v, 1);
            if (!(lane & 1)) {
                gi2[(size_t)(rbase + r) * 384 + (col >> 1)] = packf16(v, vn);
            }
        }
    }
}

// ---------------------------------------------------------------------------
// Kernel C: R7 shell + v_pk_fma_f16 dot phase.  512 threads (2 waves/SIMD).
// Thread t: a=t>>2, q=t&3; chunk c=q, rows {j*128+a} j=0..5 (192 u32 wf).
// Dot phase: 192 pk_fma, packed operands end-to-end, same-acc ops 6 apart
// (latency-covered).  f16-half partial sums (32 products each) -> f32
// combine -> quad-DPP butterfly -> in-register gates (gi2 f16, bias-folded).
// ONE barrier per step.
// ---------------------------------------------------------------------------
__global__ __launch_bounds__(512, 2) void gru_scan_pk(
    const uint32_t* __restrict__ gi2,   // [2*64][512][384] u32 (f16x2 col-pairs)
    const uint32_t* __restrict__ wpk,
    const float* __restrict__ h0f, const float* __restrict__ h0b,
    const float* __restrict__ bhf, const float* __restrict__ bhb,
    float* __restrict__ out)
{
    __shared__ __align__(16) uint32_t hpk[2][4 * 36];  // 4 chunks, 32 u32 + 4 pad

    const int bx = blockIdx.x;
    const int d  = bx >> 6;
    const int b  = bx & 63;
    const int t  = threadIdx.x;       // 0..511
    const int a  = t >> 2;            // 0..127
    const int q  = t & 3;             // quad slot == k-chunk c
    const int o  = (q < 2) ? a : (128 + a);   // owned output index

    const float* __restrict__ bh = d ? bhb : bhf;
    const float* __restrict__ h0 = d ? h0b : h0f;

    // ---- weights into registers (coalesced; one-time) ----
    const uint32_t* __restrict__ wp = wpk + (size_t)d * 98304;
    uint32_t wf[192];
#pragma unroll
    for (int jm = 0; jm < 192; ++jm) wf[jm] = wp[(size_t)jm * 512 + t];

    // ---- h0: register h_prev + packed f16x2 into hpk[0] ----
    float hp = h0[(size_t)b * HH + o];
    {
        float hnb = __shfl_down(hp, 4);       // output o+1's value (even a)
        if (!(a & 1) && !(q & 1)) {           // q==0 (m=a/2) or q==2 (m=64+a/2)
            int m = (q == 0) ? (a >> 1) : (64 + (a >> 1));
            hpk[0][(m >> 5) * 36 + (m & 31)] = packf16(hp, hnb);
        }
    }

    // n-gate recurrent bias (r/z bh folded into gi2 by the GEMM)
    const float bbn = bh[512 + o];

    const int dir = d ? -1 : 1;
    int ta = d ? (TT - 1) : 0;
    const uint32_t* __restrict__ g2 =
        gi2 + ((size_t)(d * 64 + b) * TT + ta) * 384;
    const int gco = o >> 1;
    const int shf = (a & 1) * 16;

    uint32_t gr = g2[gco], gz = g2[128 + gco], gn = g2[256 + gco];

    __syncthreads();

    for (int s = 0; s < TT; ++s) {
        const int cur = s & 1;

        const uint32_t grc = gr, gzc = gz, gnc = gn;
        if (s + 1 < TT) {
            g2 += (ptrdiff_t)dir * 384;
            gr = g2[gco]; gz = g2[128 + gco]; gn = g2[256 + gco];
        }

        // ---- dot phase: 8 uint4 broadcast reads, 192 v_pk_fma_f16 ----
        const uint32_t* __restrict__ hb = &hpk[cur][q * 36];
        f16x2 accp[6] = {};
#pragma unroll
        for (int q8 = 0; q8 < 8; ++q8) {
            uint4 h4 = *(const uint4*)&hb[q8 * 4];
            uint32_t he[4] = {h4.x, h4.y, h4.z, h4.w};
#pragma unroll
            for (int e = 0; e < 4; ++e) {
#pragma unroll
                for (int j = 0; j < 6; ++j) {
                    accp[j] = pkfma(wf[j * 32 + q8 * 4 + e], he[e], accp[j]);
                }
            }
        }

        // ---- combine halves in f32, then quad butterfly (no LDS) ----
        float acc[6];
#pragma unroll
        for (int j = 0; j < 6; ++j)
            acc[j] = (float)accp[j].x + (float)accp[j].y;
#pragma unroll
        for (int j = 0; j < 6; ++j) {
            acc[j] = qadd<0xB1>(acc[j]);   // quad_perm [1,0,3,2]  (xor 1)
            acc[j] = qadd<0x4E>(acc[j]);   // quad_perm [2,3,0,1]  (xor 2)
        }

        // output a (q<2): r=acc[0], z=acc[2], n=acc[4]
        // output 128+a (q>=2): r=acc[1], z=acc[3], n=acc[5]
        float hr = (q < 2) ? acc[0] : acc[1];
        float hz = (q < 2) ? acc[2] : acc[3];
        float hn = ((q < 2) ? acc[4] : acc[5]) + bbn;

        float ir  = cvt16(grc >> shf);
        float iz  = cvt16(gzc >> shf);
        float inn = cvt16(gnc >> shf);

        float rg = sigf(ir + hr);
        float zg = sigf(iz + hz);
        float ng = tanh_fast(fmaf(rg, hn, inn));
        float hnew = tanh_fast(fmaf(zg, hp - ng, ng));
        hp = hnew;
        if (!(q & 1))
            out[((size_t)b * TT + ta) * (2 * HH) + d * HH + o] = hnew;

        float hnb = __shfl_down(hnew, 4);     // output o+1's value (even a)
        if (!(a & 1) && !(q & 1)) {
            int m = (q == 0) ? (a >> 1) : (64 + (a >> 1));
            hpk[cur ^ 1][(m >> 5) * 36 + (m & 31)] = packf16(hnew, hnb);
        }
        ta += dir;
        __syncthreads();
    }
}

// ---------------------------------------------------------------------------
// Fallback scan (ws too small): unchanged known-good path.
// ---------------------------------------------------------------------------
__global__ __launch_bounds__(768) void gru_scan_fallback(
    const float* __restrict__ x,
    const float* __restrict__ h0f, const float* __restrict__ h0b,
    const float* __restrict__ Wif, const float* __restrict__ bif_,
    const float* __restrict__ Whf, const float* __restrict__ bhf,
    const float* __restrict__ Wib, const float* __restrict__ bib_,
    const float* __restrict__ Whb, const float* __restrict__ bhb,
    float* __restrict__ out)
{
    __shared__ __align__(16) float hbuf[2][HH];
    __shared__ float gh_s[GG];
    __shared__ float gi_s[GG];
    __shared__ __align__(16) float xrow[II];

    const int bx  = blockIdx.x;
    const int d   = bx >> 6;
    const int b   = bx & 63;
    const int tid = threadIdx.x;

    const float* __restrict__ Wh = d ? Whb : Whf;
    const float* __restrict__ bh = d ? bhb : bhf;
    const float* __restrict__ Wi = d ? Wib : Wif;
    const float* __restrict__ bi = d ? bib_ : bif_;
    const float* __restrict__ h0 = d ? h0b : h0f;

    if (tid < HH) hbuf[0][tid] = h0[(size_t)b * HH + tid];

    const float bh_row = bh[tid];
    const float bi_row = bi[tid];
    const float4* __restrict__ whr = (const float4*)(Wh + (size_t)tid * II);
    const float4* __restrict__ wir = (const float4*)(Wi + (size_t)tid * II);

    __syncthreads();

    for (int s = 0; s < TT; ++s) {
        const int ta  = d ? (TT - 1 - s) : s;
        const int cur = s & 1;

        if (tid < II) xrow[tid] = x[((size_t)b * TT + ta) * II + tid];
        __syncthreads();

        const float4* hv4 = (const float4*)hbuf[cur];
        float a0 = 0.f, a1 = 0.f, a2 = 0.f, a3 = 0.f;
#pragma unroll 4
        for (int k = 0; k < II / 4; k += 4) {
            float4 w0 = whr[k], w1 = whr[k + 1], w2 = whr[k + 2], w3 = whr[k + 3];
            float4 q0 = hv4[k], q1 = hv4[k + 1], q2 = hv4[k + 2], q3 = hv4[k + 3];
            a0 += w0.x * q0.x + w0.y * q0.y + w0.z * q0.z + w0.w * q0.w;
            a1 += w1.x * q1.x + w1.y * q1.y + w1.z * q1.z + w1.w * q1.w;
            a2 += w2.x * q2.x + w2.y * q2.y + w2.z * q2.z + w2.w * q2.w;
            a3 += w3.x * q3.x + w3.y * q3.y + w3.z * q3.z + w3.w * q3.w;
        }
        gh_s[tid] = (a0 + a1) + (a2 + a3) + bh_row;

        const float4* xv4 = (const float4*)xrow;
        float c0 = 0.f, c1 = 0.f, c2 = 0.f, c3 = 0.f;
#pragma unroll 4
        for (int k = 0; k < II / 4; k += 4) {
            float4 w0 = wir[k], w1 = wir[k + 1], w2 = wir[k + 2], w3 = wir[k + 3];
            float4 q0 = xv4[k], q1 = xv4[k + 1], q2 = xv4[k + 2], q3 = xv4[k + 3];
            c0 += w0.x * q0.x + w0.y * q0.y + w0.z * q0.z + w0.w * q0.w;
            c1 += w1.x * q1.x + w1.y * q1.y + w1.z * q1.z + w1.w * q1.w;
            c2 += w2.x * q2.x + w2.y * q2.y + w2.z * q2.z + w2.w * q2.w;
            c3 += w3.x * q3.x + w3.y * q3.y + w3.z * q3.z + w3.w * q3.w;
        }
        gi_s[tid] = (c0 + c1) + (c2 + c3) + bi_row;
        __syncthreads();

        if (tid < HH) {
            float ir = gi_s[tid], iz = gi_s[HH + tid], inn = gi_s[2 * HH + tid];
            float hr = gh_s[tid], hz = gh_s[HH + tid], hn = gh_s[2 * HH + tid];
            float r  = sigf(ir + hr);
            float z  = sigf(iz + hz);
            float n  = tanh_fast(inn + r * hn);
            float hp = hbuf[cur][tid];
            float hnew = tanh_fast((1.f - z) * n + z * hp);
            hbuf[cur ^ 1][tid] = hnew;
            out[((size_t)b * TT + ta) * (2 * HH) + d * HH + tid] = hnew;
        }
        __syncthreads();
    }
}

// ---------------------------------------------------------------------------
extern "C" void kernel_launch(void* const* d_in, const int* in_sizes, int n_in,
                              void* d_out, int out_size, void* d_ws, size_t ws_size,
                              hipStream_t stream)
{
    const float* x   = (const float*)d_in[0];
    const float* h0f = (const float*)d_in[1];
    const float* h0b = (const float*)d_in[2];
    const float* Wif = (const float*)d_in[3];
    const float* Whf = (const float*)d_in[4];
    const float* bif = (const float*)d_in[5];
    const float* bhf = (const float*)d_in[6];
    const float* Wib = (const float*)d_in[7];
    const float* Whb = (const float*)d_in[8];
    const float* bib = (const float*)d_in[9];
    const float* bhb = (const float*)d_in[10];
    float* out = (float*)d_out;

    const size_t gi2_bytes = (size_t)2 * BB * TT * 384 * sizeof(uint32_t); // 100,663,296
    const size_t wpk_bytes = (size_t)2 * 98304 * sizeof(uint32_t);        //     786,432

    if (ws_size >= gi2_bytes + wpk_bytes) {
        uint32_t* gi2 = (uint32_t*)d_ws;
        uint32_t* wpk = (uint32_t*)((char*)d_ws + gi2_bytes);

        pack_wh<<<768, 256, 0, stream>>>(Whf, Whb, wpk);

        gi_gemm_mfma2<<<12288, 256, 0, stream>>>(x, Wif, bif, Wib, bib,
                                                 bhf, bhb, gi2);

        gru_scan_pk<<<128, 512, 0, stream>>>(gi2, wpk, h0f, h0b, bhf, bhb, out);
    } else {
        gru_scan_fallback<<<128, 768, 0, stream>>>(
            x, h0f, h0b, Wif, bif, Whf, bhf, Wib, bib, Whb, bhb, out);
    }
}